// Round 7
// baseline (649.979 us; speedup 1.0000x reference)
//
#include <hip/hip_runtime.h>
#include <math.h>

static constexpr int N = 20000;       // nodes
static constexpr int E = 8192;        // hyperedges
static constexpr int F = 128;         // feature dim
static constexpr int NP = 20480;      // padded node count (K for gemmB; 1024*20)
static constexpr int NP2 = 20096;     // padded node count for gemmC output planes (157*128)
static constexpr int PREP_REAL = 1000;    // blocks of k_prep carrying real rows (20 each)
static constexpr int KS_B = 8;        // gemmB split-K
static constexpr int KS_C = 4;        // gemmC split-K

typedef short bf16x8 __attribute__((ext_vector_type(8)));
typedef float f32x4 __attribute__((ext_vector_type(4)));

__device__ __forceinline__ float gelu_erf(float x) {
    return 0.5f * x * (1.0f + erff(x * 0.70710678118654752440f));
}
__device__ __forceinline__ ushort f2bf(float f) {
    unsigned u = __float_as_uint(f);
    return (ushort)((u + 0x7FFFu + ((u >> 16) & 1u)) >> 16);
}

// ---------------- lwT[k][f] = lin_w[f][k] ----------------
__global__ void k_transpose_lw(const float* __restrict__ lin_w, float* __restrict__ lwT) {
    int idx = blockIdx.x * 256 + threadIdx.x;
    if (idx < F * F) {
        int k = idx >> 7, f = idx & 127;
        lwT[idx] = lin_w[f * F + k];
    }
}

// ---------------- prep: stream H -> Dv, DeP (col partials), Hbs = bf16(H) (UNscaled) ------
// grid 1024 x 256; 20 rows per block. NO barrier inside the row loop: the bf16
// store does not depend on the row sum, so loads/stores stream at full BW.
__global__ void k_prep(const float* __restrict__ H, float* __restrict__ Dv,
                       float* __restrict__ DeP, ushort* __restrict__ Hbs) {
    const int tid = threadIdx.x, lane = tid & 63, wid = tid >> 6;
    const int r0 = blockIdx.x * 20;
    if (r0 >= N) {            // pad rows [N, NP): Hbs = 0
        ushort4 z = make_ushort4(0, 0, 0, 0);
        for (int r = 0; r < 20; ++r) {
            ushort* orow = Hbs + (size_t)(r0 + r) * E;
#pragma unroll
            for (int j = 0; j < 8; ++j) *(ushort4*)(orow + j * 1024 + tid * 4) = z;
        }
        return;
    }
    __shared__ float rp[20][4];
    float4 ca[8];
#pragma unroll
    for (int j = 0; j < 8; ++j) ca[j] = make_float4(0.f, 0.f, 0.f, 0.f);
    for (int r = 0; r < 20; ++r) {
        const float* row = H + (size_t)(r0 + r) * E;
        ushort* orow = Hbs + (size_t)(r0 + r) * E;
        float rs = 0.f;
#pragma unroll
        for (int j = 0; j < 8; ++j) {
            float4 v = *(const float4*)(row + j * 1024 + tid * 4);
            ca[j].x += v.x; ca[j].y += v.y; ca[j].z += v.z; ca[j].w += v.w;
            rs += (v.x + v.y) + (v.z + v.w);
            ushort4 b;
            b.x = f2bf(v.x); b.y = f2bf(v.y); b.z = f2bf(v.z); b.w = f2bf(v.w);
            *(ushort4*)(orow + j * 1024 + tid * 4) = b;
        }
#pragma unroll
        for (int off = 32; off > 0; off >>= 1) rs += __shfl_xor(rs, off, 64);
        if (lane == 0) rp[r][wid] = rs;
    }
    __syncthreads();
    if (tid < 20) Dv[r0 + tid] = rp[tid][0] + rp[tid][1] + rp[tid][2] + rp[tid][3];
    float* dp = DeP + (size_t)blockIdx.x * E;
#pragma unroll
    for (int j = 0; j < 8; ++j) *(float4*)(dp + j * 1024 + tid * 4) = ca[j];
}

// ---------------- se[e] = W[e] / clip(sum_p DeP[p][e], 1) ----------------
__global__ void k_se(const float* __restrict__ DeP, const float* __restrict__ W,
                     float* __restrict__ se) {
    __shared__ float red[4][64];
    const int tid = threadIdx.x;
    const int c = blockIdx.x * 64 + (tid & 63);
    const int pg = tid >> 6;
    float s = 0.f;
    for (int p = pg; p < PREP_REAL; p += 4) s += DeP[(size_t)p * E + c];
    red[pg][tid & 63] = s;
    __syncthreads();
    if (tid < 64) {
        float d = red[0][tid] + red[1][tid] + red[2][tid] + red[3][tid];
        int e = blockIdx.x * 64 + tid;
        se[e] = W[e] / fmaxf(d, 1.f);
    }
}

// ---------------- y[v][f] = bf16(dvis[v] * (x@lw^T + b))  (dvis inline from Dv) ----------
__global__ void k_xw(const float* __restrict__ x, const float* __restrict__ lwT,
                     const float* __restrict__ lin_b, const float* __restrict__ Dv,
                     ushort* __restrict__ y) {
    __shared__ __align__(16) float xs[4][F];
    int f = threadIdx.x;            // 128 threads
    int r0 = blockIdx.x * 4;
    if (r0 >= N) {
#pragma unroll
        for (int j = 0; j < 4; ++j) y[(size_t)(r0 + j) * F + f] = 0;
        return;
    }
#pragma unroll
    for (int j = 0; j < 4; ++j) xs[j][f] = x[(size_t)(r0 + j) * F + f];
    __syncthreads();
    float s0 = rsqrtf(fmaxf(Dv[r0 + 0], 1.f));
    float s1 = rsqrtf(fmaxf(Dv[r0 + 1], 1.f));
    float s2 = rsqrtf(fmaxf(Dv[r0 + 2], 1.f));
    float s3 = rsqrtf(fmaxf(Dv[r0 + 3], 1.f));
    float b = lin_b[f];
    float a0 = b, a1 = b, a2 = b, a3 = b;
#pragma unroll 4
    for (int k = 0; k < F; ++k) {
        float lw = lwT[k * F + f];
        a0 += xs[0][k] * lw;
        a1 += xs[1][k] * lw;
        a2 += xs[2][k] * lw;
        a3 += xs[3][k] * lw;
    }
    y[(size_t)(r0 + 0) * F + f] = f2bf(s0 * a0);
    y[(size_t)(r0 + 1) * F + f] = f2bf(s1 * a1);
    y[(size_t)(r0 + 2) * F + f] = f2bf(s2 * a2);
    y[(size_t)(r0 + 3) * F + f] = f2bf(s3 * a3);
}

// ---------------- yT[f][v] = y[v][f]  (bf16 64x64 tile transpose) ----------------
__global__ void k_ytrans(const ushort* __restrict__ y, ushort* __restrict__ yT) {
    __shared__ __align__(16) char tl[8192];
    int tid = threadIdx.x;
    int r0 = (blockIdx.x >> 1) * 64;   // v
    int c0 = (blockIdx.x & 1) * 64;    // f
#pragma unroll
    for (int c = 0; c < 2; ++c) {
        int lin = c * 256 + tid;
        int row = lin >> 3, ch = lin & 7;
        uint4 v = *(const uint4*)(y + (size_t)(r0 + row) * F + c0 + ch * 8);
        int key = ((row ^ (row >> 3)) & 7) << 4;
        *(uint4*)(tl + row * 128 + ((ch * 16) ^ key)) = v;
    }
    __syncthreads();
#pragma unroll
    for (int c = 0; c < 2; ++c) {
        int lin = c * 256 + tid;
        int fl = lin >> 3, vch = lin & 7;
        unsigned u[4];
#pragma unroll
        for (int qq = 0; qq < 4; ++qq) {
            int r1 = vch * 8 + qq * 2, r2 = r1 + 1;
            ushort a = *(const ushort*)(tl + r1 * 128 + ((fl * 2) ^ (((r1 ^ (r1 >> 3)) & 7) << 4)));
            ushort b = *(const ushort*)(tl + r2 * 128 + ((fl * 2) ^ (((r2 ^ (r2 >> 3)) & 7) << 4)));
            u[qq] = (unsigned)a | ((unsigned)b << 16);
        }
        uint4 o = make_uint4(u[0], u[1], u[2], u[3]);
        *(uint4*)(yT + (size_t)(c0 + fl) * NP + r0 + vch * 8) = o;
    }
}

// ---------------- tsT[f][e] = bf16(se[e] * sum_ks tB[ks][e][f])  (reduce + transpose) ------
__global__ void k_tst(const float* __restrict__ tB, const float* __restrict__ se,
                      ushort* __restrict__ tsT) {
    __shared__ __align__(16) char tl[8192];
    int tid = threadIdx.x;
    int r0 = (blockIdx.x >> 1) * 64;   // e
    int c0 = (blockIdx.x & 1) * 64;    // f
#pragma unroll
    for (int c = 0; c < 4; ++c) {
        int lin = c * 256 + tid;
        int row = lin >> 4, ch = lin & 15;
        size_t base = (size_t)(r0 + row) * F + c0 + ch * 4;
        float4 v = make_float4(0.f, 0.f, 0.f, 0.f);
#pragma unroll
        for (int ks = 0; ks < KS_B; ++ks) {
            float4 p = *(const float4*)(tB + (size_t)ks * E * F + base);
            v.x += p.x; v.y += p.y; v.z += p.z; v.w += p.w;
        }
        float s = se[r0 + row];
        ushort4 b;
        b.x = f2bf(v.x * s); b.y = f2bf(v.y * s); b.z = f2bf(v.z * s); b.w = f2bf(v.w * s);
        int key = ((row ^ (row >> 3)) & 7) << 4;
        *(ushort4*)(tl + row * 128 + ((ch * 8) ^ key)) = b;
    }
    __syncthreads();
#pragma unroll
    for (int c = 0; c < 2; ++c) {
        int lin = c * 256 + tid;
        int fl = lin >> 3, vch = lin & 7;
        unsigned u[4];
#pragma unroll
        for (int qq = 0; qq < 4; ++qq) {
            int r1 = vch * 8 + qq * 2, r2 = r1 + 1;
            ushort a = *(const ushort*)(tl + r1 * 128 + ((fl * 2) ^ (((r1 ^ (r1 >> 3)) & 7) << 4)));
            ushort b = *(const ushort*)(tl + r2 * 128 + ((fl * 2) ^ (((r2 ^ (r2 >> 3)) & 7) << 4)));
            u[qq] = (unsigned)a | ((unsigned)b << 16);
        }
        uint4 o = make_uint4(u[0], u[1], u[2], u[3]);
        *(uint4*)(tsT + (size_t)(c0 + fl) * E + r0 + vch * 8) = o;
    }
}

// ---------------- gemmB (MFMA): tB[ks][e][f] = sum_{v in chunk} Hbs[v][e] * yT[f][v] ------
// Double-buffered LDS, ONE barrier per K-step.
__global__ __launch_bounds__(256) void k_gemmB(const ushort* __restrict__ Hbs,
                                               const ushort* __restrict__ yT,
                                               float* __restrict__ tB) {
    __shared__ __align__(16) char lA[2][16384];   // As[e 128][v 64] bf16, key ((e>>3)&7)<<4
    __shared__ __align__(16) char lB[2][16384];   // Bs[f 128][v 64] bf16, key (f&7)<<4
    const int tid = threadIdx.x;
    const int m0 = (blockIdx.x & 63) * 128;    // e tile
    const int ks = blockIdx.x >> 6;
    const int k0 = ks * 2560;                  // v chunk
    const int lane = tid & 63, w = tid >> 6;
    const int wm = (w & 1) * 64, wn = (w >> 1) * 64;
    const int lrow = lane & 15, g16 = (lane >> 4) * 16;
    const int NSTEP = 40;

    const int vq = tid >> 4;
    const int e8 = (tid & 15) * 8;
    const ushort* pa = Hbs + (size_t)(k0 + vq * 4) * E + m0 + e8;
    const int abase = e8 * 128 + ((vq * 8) ^ ((tid & 7) << 4));

    int bwoff[4];
    const uint4* pb[4];
#pragma unroll
    for (int c = 0; c < 4; ++c) {
        int lin = c * 256 + tid;
        int row = lin >> 3, ch = lin & 7;
        bwoff[c] = row * 128 + ((ch * 16) ^ ((row & 7) << 4));
        pb[c] = (const uint4*)(yT + (size_t)row * NP + k0 + ch * 8);
    }
    int aoff[4][2], boff[4][2];
#pragma unroll
    for (int f = 0; f < 4; ++f)
#pragma unroll
        for (int kk = 0; kk < 2; ++kk) {
            int ma = wm + f * 16 + lrow;
            aoff[f][kk] = ma * 128 + (((kk * 64) + g16) ^ (((ma >> 3) & 7) << 4));
            int nb = wn + f * 16 + lrow;
            boff[f][kk] = nb * 128 + (((kk * 64) + g16) ^ ((nb & 7) << 4));
        }

    f32x4 zero4 = {0.f, 0.f, 0.f, 0.f};
    f32x4 acc[4][4];
#pragma unroll
    for (int i = 0; i < 4; ++i)
#pragma unroll
        for (int j = 0; j < 4; ++j) acc[i][j] = zero4;

    uint4 ra[4], rb[4];
    // prologue: tile0 -> regs -> buf0; tile1 -> regs
#pragma unroll
    for (int r = 0; r < 4; ++r) ra[r] = *(const uint4*)(pa + (size_t)r * E);
#pragma unroll
    for (int c = 0; c < 4; ++c) rb[c] = pb[c][0];
    {
        const ushort* u0 = (const ushort*)&ra[0];
        const ushort* u1 = (const ushort*)&ra[1];
        const ushort* u2 = (const ushort*)&ra[2];
        const ushort* u3 = (const ushort*)&ra[3];
#pragma unroll
        for (int i = 0; i < 8; ++i) {
            uint2 wv;
            wv.x = (unsigned)u0[i] | ((unsigned)u1[i] << 16);
            wv.y = (unsigned)u2[i] | ((unsigned)u3[i] << 16);
            *(uint2*)(lA[0] + abase + i * 128) = wv;
        }
#pragma unroll
        for (int c = 0; c < 4; ++c) *(uint4*)(lB[0] + bwoff[c]) = rb[c];
    }
    pa += (size_t)64 * E;
#pragma unroll
    for (int r = 0; r < 4; ++r) ra[r] = *(const uint4*)(pa + (size_t)r * E);
#pragma unroll
    for (int c = 0; c < 4; ++c) { pb[c] += 8; rb[c] = pb[c][0]; }
    __syncthreads();

    for (int kt = 0; kt < NSTEP; ++kt) {
        const int cur = kt & 1;
        if (kt + 1 < NSTEP) {
            // write tile kt+1 into buf cur^1
            const ushort* u0 = (const ushort*)&ra[0];
            const ushort* u1 = (const ushort*)&ra[1];
            const ushort* u2 = (const ushort*)&ra[2];
            const ushort* u3 = (const ushort*)&ra[3];
#pragma unroll
            for (int i = 0; i < 8; ++i) {
                uint2 wv;
                wv.x = (unsigned)u0[i] | ((unsigned)u1[i] << 16);
                wv.y = (unsigned)u2[i] | ((unsigned)u3[i] << 16);
                *(uint2*)(lA[cur ^ 1] + abase + i * 128) = wv;
            }
#pragma unroll
            for (int c = 0; c < 4; ++c) *(uint4*)(lB[cur ^ 1] + bwoff[c]) = rb[c];
        }
        if (kt + 2 < NSTEP) {
            pa += (size_t)64 * E;
#pragma unroll
            for (int r = 0; r < 4; ++r) ra[r] = *(const uint4*)(pa + (size_t)r * E);
#pragma unroll
            for (int c = 0; c < 4; ++c) { pb[c] += 8; rb[c] = pb[c][0]; }
        }
#pragma unroll
        for (int kk = 0; kk < 2; ++kk) {
            bf16x8 av[4], bv[4];
#pragma unroll
            for (int f = 0; f < 4; ++f) av[f] = *(const bf16x8*)(lA[cur] + aoff[f][kk]);
#pragma unroll
            for (int f = 0; f < 4; ++f) bv[f] = *(const bf16x8*)(lB[cur] + boff[f][kk]);
#pragma unroll
            for (int i = 0; i < 4; ++i)
#pragma unroll
                for (int j = 0; j < 4; ++j)
                    acc[i][j] = __builtin_amdgcn_mfma_f32_16x16x32_bf16(av[i], bv[j], acc[i][j], 0, 0, 0);
        }
        if (kt + 1 < NSTEP) __syncthreads();
    }
    float* plane = tB + (size_t)ks * E * F;
    const int orow = (lane >> 4) * 4, ocol = lane & 15;
#pragma unroll
    for (int i = 0; i < 4; ++i)
#pragma unroll
        for (int j = 0; j < 4; ++j) {
            int gm = m0 + wm + i * 16 + orow;
            int gn = wn + j * 16 + ocol;
#pragma unroll
            for (int q = 0; q < 4; ++q)
                plane[(size_t)(gm + q) * F + gn] = acc[i][j][q];
        }
}

// ---------------- gemmC (MFMA): C2P[ks][n][f] = sum_{e in chunk} Hbs[n][e] * tsT[f][e] -----
// Double-buffered LDS, ONE barrier per K-step.
__global__ __launch_bounds__(256) void k_gemmC(const ushort* __restrict__ Hbs,
                                               const ushort* __restrict__ tsT,
                                               float* __restrict__ C2P) {
    __shared__ __align__(16) char lA[2][16384];
    __shared__ __align__(16) char lB[2][16384];
    const int tid = threadIdx.x;
    const int m0 = (blockIdx.x % 157) * 128;
    const int ks = blockIdx.x / 157;
    const int k0 = ks * 2048;
    const int lane = tid & 63, w = tid >> 6;
    const int wm = (w & 1) * 64, wn = (w >> 1) * 64;
    const int lrow = lane & 15, g16 = (lane >> 4) * 16;
    const int NSTEP = 32;

    int awoff[4], bwoff[4];
    const uint4* pA[4];
    const uint4* pB[4];
#pragma unroll
    for (int c = 0; c < 4; ++c) {
        int lin = c * 256 + tid;
        int row = lin >> 3, ch = lin & 7;
        awoff[c] = row * 128 + ((ch * 16) ^ ((row & 7) << 4));
        bwoff[c] = awoff[c];
        pA[c] = (const uint4*)(Hbs + (size_t)(m0 + row) * E + k0 + ch * 8);
        pB[c] = (const uint4*)(tsT + (size_t)row * E + k0 + ch * 8);
    }
    int aoff[4][2], boff[4][2];
#pragma unroll
    for (int f = 0; f < 4; ++f)
#pragma unroll
        for (int kk = 0; kk < 2; ++kk) {
            int ma = wm + f * 16 + lrow;
            aoff[f][kk] = ma * 128 + (((kk * 64) + g16) ^ ((ma & 7) << 4));
            int nb = wn + f * 16 + lrow;
            boff[f][kk] = nb * 128 + (((kk * 64) + g16) ^ ((nb & 7) << 4));
        }

    f32x4 zero4 = {0.f, 0.f, 0.f, 0.f};
    f32x4 acc[4][4];
#pragma unroll
    for (int i = 0; i < 4; ++i)
#pragma unroll
        for (int j = 0; j < 4; ++j) acc[i][j] = zero4;

    uint4 ra[4], rb[4];
#pragma unroll
    for (int c = 0; c < 4; ++c) { ra[c] = pA[c][0]; rb[c] = pB[c][0]; }
#pragma unroll
    for (int c = 0; c < 4; ++c) {
        *(uint4*)(lA[0] + awoff[c]) = ra[c];
        *(uint4*)(lB[0] + bwoff[c]) = rb[c];
    }
#pragma unroll
    for (int c = 0; c < 4; ++c) {
        pA[c] += 8; pB[c] += 8;
        ra[c] = pA[c][0]; rb[c] = pB[c][0];
    }
    __syncthreads();

    for (int kt = 0; kt < NSTEP; ++kt) {
        const int cur = kt & 1;
        if (kt + 1 < NSTEP) {
#pragma unroll
            for (int c = 0; c < 4; ++c) {
                *(uint4*)(lA[cur ^ 1] + awoff[c]) = ra[c];
                *(uint4*)(lB[cur ^ 1] + bwoff[c]) = rb[c];
            }
        }
        if (kt + 2 < NSTEP) {
#pragma unroll
            for (int c = 0; c < 4; ++c) {
                pA[c] += 8; pB[c] += 8;
                ra[c] = pA[c][0]; rb[c] = pB[c][0];
            }
        }
#pragma unroll
        for (int kk = 0; kk < 2; ++kk) {
            bf16x8 av[4], bv[4];
#pragma unroll
            for (int f = 0; f < 4; ++f) av[f] = *(const bf16x8*)(lA[cur] + aoff[f][kk]);
#pragma unroll
            for (int f = 0; f < 4; ++f) bv[f] = *(const bf16x8*)(lB[cur] + boff[f][kk]);
#pragma unroll
            for (int i = 0; i < 4; ++i)
#pragma unroll
                for (int j = 0; j < 4; ++j)
                    acc[i][j] = __builtin_amdgcn_mfma_f32_16x16x32_bf16(av[i], bv[j], acc[i][j], 0, 0, 0);
        }
        if (kt + 1 < NSTEP) __syncthreads();
    }
    float* plane = C2P + (size_t)ks * NP2 * F;
    const int orow = (lane >> 4) * 4, ocol = lane & 15;
#pragma unroll
    for (int i = 0; i < 4; ++i)
#pragma unroll
        for (int j = 0; j < 4; ++j) {
            int gm = m0 + wm + i * 16 + orow;
            int gn = wn + j * 16 + ocol;
#pragma unroll
            for (int q = 0; q < 4; ++q)
                plane[(size_t)(gm + q) * F + gn] = acc[i][j][q];
        }
}

// ---------------- out = gelu(dvis[n] * sum_ks C2P[ks][n][f])  (dvis inline) ----------------
__global__ void k_fin_out(const float* __restrict__ C2P, const float* __restrict__ Dv,
                          float* __restrict__ out) {
    int i4 = blockIdx.x * 256 + threadIdx.x;
    if (i4 < N * F / 4) {
        int n = i4 >> 5;
        float s = rsqrtf(fmaxf(Dv[n], 1.f));
        float4 v = make_float4(0.f, 0.f, 0.f, 0.f);
#pragma unroll
        for (int ks = 0; ks < KS_C; ++ks) {
            float4 p = reinterpret_cast<const float4*>(C2P + (size_t)ks * NP2 * F)[i4];
            v.x += p.x; v.y += p.y; v.z += p.z; v.w += p.w;
        }
        float4 o;
        o.x = gelu_erf(s * v.x);
        o.y = gelu_erf(s * v.y);
        o.z = gelu_erf(s * v.z);
        o.w = gelu_erf(s * v.w);
        reinterpret_cast<float4*>(out)[i4] = o;
    }
}

extern "C" void kernel_launch(void* const* d_in, const int* in_sizes, int n_in,
                              void* d_out, int out_size, void* d_ws, size_t ws_size,
                              hipStream_t stream) {
    const float* x     = (const float*)d_in[0];
    const float* H     = (const float*)d_in[1];
    const float* W     = (const float*)d_in[2];
    const float* lin_w = (const float*)d_in[3];
    const float* lin_b = (const float*)d_in[4];
    float* out = (float*)d_out;

    // workspace layout (bytes): ~456.6 MiB
    char* ws = (char*)d_ws;
    ushort* Hbs = (ushort*)ws;                                   // NP*E*2      = 335,544,320
    ushort* y   = (ushort*)(ws + 335544320);                     // NP*F*2      = 5,242,880
    ushort* yT  = (ushort*)(ws + 340787200);                     // F*NP*2      = 5,242,880
    float*  tB  = (float*) (ws + 346030080);                     // 8*E*F*4     = 33,554,432
    ushort* tsT = (ushort*)(ws + 379584512);                     // F*E*2       = 2,097,152
    float*  C2P = (float*) (ws + 381681664);                     // 4*NP2*F*4   = 41,156,608
    float*  DeP = (float*) (ws + 422838272);                     // 1024*E*4    = 33,554,432
    float*  Dv  = (float*) (ws + 456392704);                     // N*4         = 80,000
    float*  se  = (float*) (ws + 456472704);                     // E*4
    float*  lwT = (float*) (ws + 456505472);                     // F*F*4

    k_transpose_lw<<<64, 256, 0, stream>>>(lin_w, lwT);
    k_prep<<<NP / 20, 256, 0, stream>>>(H, Dv, DeP, Hbs);
    k_se<<<E / 64, 256, 0, stream>>>(DeP, W, se);
    k_xw<<<NP / 4, 128, 0, stream>>>(x, lwT, lin_b, Dv, y);
    k_ytrans<<<(NP / 64) * 2, 256, 0, stream>>>(y, yT);
    k_gemmB<<<64 * KS_B, 256, 0, stream>>>(Hbs, yT, tB);
    k_tst<<<(E / 64) * 2, 256, 0, stream>>>(tB, se, tsT);
    k_gemmC<<<157 * KS_C, 256, 0, stream>>>(Hbs, tsT, C2P);
    k_fin_out<<<(N * F / 4 + 255) / 256, 256, 0, stream>>>(C2P, Dv, out);
}